// Round 2
// baseline (1789.223 us; speedup 1.0000x reference)
//
#include <hip/hip_runtime.h>
#include <hip/hip_bf16.h>

#define BATCH 16
#define NPTS  4096
#define NSAMP 1024   // S = N * 0.25
#define KNB   32     // nsample
#define DFEAT 64

#define FPS_T   512
#define FPS_PPT (NPTS / FPS_T)   // 8 points per thread
#define FPS_W   (FPS_T / 64)     // 8 waves

// ---------------------------------------------------------------------------
// Kernel 1: farthest point sampling. One block per batch, 512 threads.
// Coords + min_d in registers; LDS coord copy only for centroid lookup;
// single barrier per step (double-buffered wave partials, redundant final
// reduce on every thread).
// ---------------------------------------------------------------------------
__global__ __launch_bounds__(FPS_T) void fps_kernel(const float* __restrict__ xyz,
                                                    int* __restrict__ fps_idx,
                                                    float* __restrict__ out_xyz) {
    const int b    = blockIdx.x;
    const int tid  = threadIdx.x;
    const int lane = tid & 63;
    const int wid  = tid >> 6;

    __shared__ float sx[NPTS], sy[NPTS], sz[NPTS];   // 48 KB (centroid lookup)
    __shared__ float pbv[2][FPS_W];
    __shared__ int   pbi[2][FPS_W];

    float px[FPS_PPT], py[FPS_PPT], pz[FPS_PPT], md[FPS_PPT];

    const float* base = xyz + (size_t)b * NPTS * 3;
#pragma unroll
    for (int j = 0; j < FPS_PPT; j++) {
        const int i = j * FPS_T + tid;
        const float x = base[i * 3 + 0];
        const float y = base[i * 3 + 1];
        const float z = base[i * 3 + 2];
        sx[i] = x; sy[i] = y; sz[i] = z;
        px[j] = x; py[j] = y; pz[j] = z;
        md[j] = 1e10f;
    }

    if (tid == 0) {
        fps_idx[b * NSAMP + 0] = 0;
        out_xyz[(size_t)b * 3 * NSAMP + 0 * NSAMP + 0] = base[0];
        out_xyz[(size_t)b * 3 * NSAMP + 1 * NSAMP + 0] = base[1];
        out_xyz[(size_t)b * 3 * NSAMP + 2 * NSAMP + 0] = base[2];
    }
    __syncthreads();

    int bix = 0;   // current centroid index (all threads agree)
    for (int s = 1; s < NSAMP; s++) {
        const float cx = sx[bix], cy = sy[bix], cz = sz[bix];
        float best = -1.0f;
        int   bi   = 0;
#pragma unroll
        for (int j = 0; j < FPS_PPT; j++) {
            const float dx = px[j] - cx;
            const float dy = py[j] - cy;
            const float dz = pz[j] - cz;
            // match reference rounding: no fma contraction
            const float d = __fadd_rn(__fadd_rn(__fmul_rn(dx, dx), __fmul_rn(dy, dy)),
                                      __fmul_rn(dz, dz));
            const float m = fminf(md[j], d);
            md[j] = m;
            if (m > best) { best = m; bi = j * FPS_T + tid; }  // strict >: lowest p per thread
        }
        // wave butterfly reduce: max value, lowest index on ties
#pragma unroll
        for (int off = 32; off > 0; off >>= 1) {
            const float ov = __shfl_xor(best, off);
            const int   oi = __shfl_xor(bi, off);
            if (ov > best || (ov == best && oi < bi)) { best = ov; bi = oi; }
        }
        const int par = s & 1;
        if (lane == 0) { pbv[par][wid] = best; pbi[par][wid] = bi; }
        __syncthreads();
        // every thread redundantly reduces the 8 wave partials -> no 2nd barrier
        float bv = pbv[par][0];
        bix      = pbi[par][0];
#pragma unroll
        for (int w = 1; w < FPS_W; w++) {
            const float v  = pbv[par][w];
            const int   i2 = pbi[par][w];
            if (v > bv || (v == bv && i2 < bix)) { bv = v; bix = i2; }
        }
        if (tid == 0) {
            fps_idx[b * NSAMP + s] = bix;
            out_xyz[(size_t)b * 3 * NSAMP + 0 * NSAMP + s] = sx[bix];
            out_xyz[(size_t)b * 3 * NSAMP + 1 * NSAMP + s] = sy[bix];
            out_xyz[(size_t)b * 3 * NSAMP + 2 * NSAMP + s] = sz[bix];
        }
    }
}

// ---------------------------------------------------------------------------
// Kernel 2: ball query. One wave (64 lanes) per query point.
// ---------------------------------------------------------------------------
__global__ __launch_bounds__(256) void ballq_kernel(const float* __restrict__ xyz,
                                                    const int* __restrict__ fps_idx,
                                                    int* __restrict__ grp) {
    const int q    = blockIdx.x * 4 + (threadIdx.x >> 6);
    const int lane = threadIdx.x & 63;
    const int b    = q >> 10;       // / NSAMP
    const int c    = fps_idx[q];

    const float* base = xyz + (size_t)b * NPTS * 3;
    const float cx = base[c * 3 + 0];
    const float cy = base[c * 3 + 1];
    const float cz = base[c * 3 + 2];
    const float r2 = 0.04f;         // f32(0.2*0.2)

    int* g = grp + (size_t)q * KNB;
    int cnt = 0;
    int firstCand = 0x7fffffff;

    for (int bp = 0; bp < NPTS && cnt < KNB; bp += 64) {
        const int p = bp + lane;
        const float dx = base[p * 3 + 0] - cx;
        const float dy = base[p * 3 + 1] - cy;
        const float dz = base[p * 3 + 2] - cz;
        const float d = __fadd_rn(__fadd_rn(__fmul_rn(dx, dx), __fmul_rn(dy, dy)),
                                  __fmul_rn(dz, dz));
        const bool ok = !(d > r2);
        const unsigned long long m = __ballot(ok);
        const int rank = cnt + (int)__popcll(m & ((1ull << lane) - 1ull));
        if (ok && rank < KNB) g[rank] = p;
        if (ok && rank == 0) firstCand = p;
        cnt += (int)__popcll(m);
    }

    const int found = cnt < KNB ? cnt : KNB;
    if (found < KNB) {
#pragma unroll
        for (int off = 32; off > 0; off >>= 1) {
            const int o = __shfl_xor(firstCand, off);
            firstCand = o < firstCand ? o : firstCand;
        }
        for (int r = found + lane; r < KNB; r += 64) g[r] = firstCand;
    }
}

// ---------------------------------------------------------------------------
// Kernel 3: gather + MLP(64->64 relu, 64->128 relu) + max over 32 samples.
// One wave per query; lane = channel.
// ---------------------------------------------------------------------------
__global__ __launch_bounds__(256) void mlp_kernel(const float* __restrict__ features,
                                                  const int* __restrict__ grp,
                                                  const float* __restrict__ W1,
                                                  const float* __restrict__ b1,
                                                  const float* __restrict__ W2,
                                                  const float* __restrict__ b2,
                                                  float* __restrict__ out_pts) {
    const int wid  = threadIdx.x >> 6;
    const int lane = threadIdx.x & 63;
    const int q    = blockIdx.x * 4 + wid;
    const int b    = q >> 10;
    const int s    = q & 1023;

    __shared__ float xls[4][KNB][DFEAT];   // 32 KB
    __shared__ float h1s[4][DFEAT];        // 1 KB

    float w1r[64], w2ra[64], w2rb[64];
    {
        const float4* W1v = (const float4*)(W1 + (size_t)lane * 64);
        const float4* W2a = (const float4*)(W2 + (size_t)lane * 64);
        const float4* W2b = (const float4*)(W2 + (size_t)(lane + 64) * 64);
#pragma unroll
        for (int i = 0; i < 16; i++) {
            float4 v = W1v[i];
            w1r[4 * i] = v.x; w1r[4 * i + 1] = v.y; w1r[4 * i + 2] = v.z; w1r[4 * i + 3] = v.w;
            v = W2a[i];
            w2ra[4 * i] = v.x; w2ra[4 * i + 1] = v.y; w2ra[4 * i + 2] = v.z; w2ra[4 * i + 3] = v.w;
            v = W2b[i];
            w2rb[4 * i] = v.x; w2rb[4 * i + 1] = v.y; w2rb[4 * i + 2] = v.z; w2rb[4 * i + 3] = v.w;
        }
    }
    const float b1r  = b1[lane];
    const float b2ra = b2[lane];
    const float b2rb = b2[lane + 64];

    int gi = 0;
    if (lane < KNB) gi = grp[(size_t)q * KNB + lane];
    const float* fb = features + (size_t)b * NPTS * DFEAT;
    for (int k = 0; k < KNB; k++) {
        const int idxk = __shfl(gi, k);
        xls[wid][k][lane] = fb[(size_t)idxk * DFEAT + lane];
    }
    __syncthreads();

    float m0 = 0.0f, m1 = 0.0f;   // relu outputs >= 0
    for (int k = 0; k < KNB; k++) {
        float acc = b1r;
        const float4* xk = (const float4*)xls[wid][k];
#pragma unroll
        for (int i = 0; i < 16; i++) {
            const float4 v = xk[i];
            acc = fmaf(v.x, w1r[4 * i], acc);
            acc = fmaf(v.y, w1r[4 * i + 1], acc);
            acc = fmaf(v.z, w1r[4 * i + 2], acc);
            acc = fmaf(v.w, w1r[4 * i + 3], acc);
        }
        const float h = fmaxf(acc, 0.0f);
        __syncthreads();
        h1s[wid][lane] = h;
        __syncthreads();
        float a0 = b2ra, a1 = b2rb;
        const float4* hv4 = (const float4*)h1s[wid];
#pragma unroll
        for (int i = 0; i < 16; i++) {
            const float4 v = hv4[i];
            a0 = fmaf(v.x, w2ra[4 * i], a0);
            a0 = fmaf(v.y, w2ra[4 * i + 1], a0);
            a0 = fmaf(v.z, w2ra[4 * i + 2], a0);
            a0 = fmaf(v.w, w2ra[4 * i + 3], a0);
            a1 = fmaf(v.x, w2rb[4 * i], a1);
            a1 = fmaf(v.y, w2rb[4 * i + 1], a1);
            a1 = fmaf(v.z, w2rb[4 * i + 2], a1);
            a1 = fmaf(v.w, w2rb[4 * i + 3], a1);
        }
        m0 = fmaxf(m0, fmaxf(a0, 0.0f));
        m1 = fmaxf(m1, fmaxf(a1, 0.0f));
    }

    out_pts[(size_t)b * 128 * NSAMP + (size_t)lane * NSAMP + s]        = m0;
    out_pts[(size_t)b * 128 * NSAMP + (size_t)(lane + 64) * NSAMP + s] = m1;
}

extern "C" void kernel_launch(void* const* d_in, const int* in_sizes, int n_in,
                              void* d_out, int out_size, void* d_ws, size_t ws_size,
                              hipStream_t stream) {
    const float* xyz      = (const float*)d_in[0];
    const float* features = (const float*)d_in[1];
    const float* W1       = (const float*)d_in[2];
    const float* b1       = (const float*)d_in[3];
    const float* W2       = (const float*)d_in[4];
    const float* b2       = (const float*)d_in[5];

    float* out_xyz = (float*)d_out;                                  // [B,3,S]
    float* out_pts = (float*)d_out + (size_t)BATCH * 3 * NSAMP;      // [B,128,S]

    int* fps_idx = (int*)d_ws;                                       // [B,S]
    int* grp     = fps_idx + (size_t)BATCH * NSAMP;                  // [B,S,32]

    fps_kernel<<<BATCH, FPS_T, 0, stream>>>(xyz, fps_idx, out_xyz);
    ballq_kernel<<<BATCH * NSAMP / 4, 256, 0, stream>>>(xyz, fps_idx, grp);
    mlp_kernel<<<BATCH * NSAMP / 4, 256, 0, stream>>>(features, grp, W1, b1, W2, b2, out_pts);
}

// Round 3
// 961.122 us; speedup vs baseline: 1.8616x; 1.8616x over previous
//
#include <hip/hip_runtime.h>
#include <hip/hip_bf16.h>

#define BATCH 16
#define NPTS  4096
#define NSAMP 1024   // S = N * 0.25
#define KNB   32     // nsample
#define DFEAT 64

#define FPS_T   256
#define FPS_PPT (NPTS / FPS_T)   // 16 points per thread
#define FPS_W   (FPS_T / 64)     // 4 waves

// ---------------------------------------------------------------------------
// DPP-based wave64 max-reduce on packed u64 keys (pure VALU, no DS ops).
// Key = (f32_bits(value) << 32) | ~idx : max key == max value, ties -> min idx.
// Result valid in lane 63 only.
// ---------------------------------------------------------------------------
#define DPP_MAX_ROUND(cur, ctrl, rmask)                                        \
    {                                                                          \
        const int _lo = (int)(unsigned)(cur);                                  \
        const int _hi = (int)(unsigned)((cur) >> 32);                          \
        const int _tlo = __builtin_amdgcn_update_dpp(_lo, _lo, (ctrl), (rmask), 0xF, false); \
        const int _thi = __builtin_amdgcn_update_dpp(_hi, _hi, (ctrl), (rmask), 0xF, false); \
        const unsigned long long _t =                                          \
            ((unsigned long long)(unsigned)_thi << 32) | (unsigned)_tlo;       \
        if (_t > (cur)) (cur) = _t;                                            \
    }

__device__ __forceinline__ unsigned long long wave_max_key(unsigned long long cur) {
    DPP_MAX_ROUND(cur, 0x111, 0xF);  // row_shr:1
    DPP_MAX_ROUND(cur, 0x112, 0xF);  // row_shr:2
    DPP_MAX_ROUND(cur, 0x114, 0xF);  // row_shr:4
    DPP_MAX_ROUND(cur, 0x118, 0xF);  // row_shr:8  -> lane 15 of each row has row max
    DPP_MAX_ROUND(cur, 0x142, 0xA);  // row_bcast:15 -> lane 31 = max(rows 0,1); 63 = max(2,3)
    DPP_MAX_ROUND(cur, 0x143, 0xC);  // row_bcast:31 -> lane 63 = max(all)
    return cur;
}

// ---------------------------------------------------------------------------
// Kernel 1: farthest point sampling. One block per batch, 256 threads.
// Coords + min_d in registers; LDS coord copy for centroid lookup;
// DPP wave reduce + single barrier per step.
// ---------------------------------------------------------------------------
__global__ __launch_bounds__(FPS_T) void fps_kernel(const float* __restrict__ xyz,
                                                    int* __restrict__ fps_idx,
                                                    float* __restrict__ out_xyz) {
    const int b    = blockIdx.x;
    const int tid  = threadIdx.x;
    const int lane = tid & 63;
    const int wid  = tid >> 6;

    __shared__ float sx[NPTS], sy[NPTS], sz[NPTS];        // 48 KB (centroid lookup)
    __shared__ unsigned long long pw[2][FPS_W];           // wave partials, dbuf

    float px[FPS_PPT], py[FPS_PPT], pz[FPS_PPT], md[FPS_PPT];

    const float* base = xyz + (size_t)b * NPTS * 3;
#pragma unroll
    for (int j = 0; j < FPS_PPT; j++) {
        const int i = j * FPS_T + tid;
        const float x = base[i * 3 + 0];
        const float y = base[i * 3 + 1];
        const float z = base[i * 3 + 2];
        sx[i] = x; sy[i] = y; sz[i] = z;
        px[j] = x; py[j] = y; pz[j] = z;
        md[j] = 1e10f;
    }

    if (tid == 0) {
        fps_idx[b * NSAMP + 0] = 0;
        out_xyz[(size_t)b * 3 * NSAMP + 0 * NSAMP + 0] = base[0];
        out_xyz[(size_t)b * 3 * NSAMP + 1 * NSAMP + 0] = base[1];
        out_xyz[(size_t)b * 3 * NSAMP + 2 * NSAMP + 0] = base[2];
    }
    __syncthreads();

    int bix = 0;   // current centroid index (uniform across block)
    for (int s = 1; s < NSAMP; s++) {
        const float cx = sx[bix], cy = sy[bix], cz = sz[bix];
        float best = -1.0f;
        int   bi   = 0;
#pragma unroll
        for (int j = 0; j < FPS_PPT; j++) {
            const float dx = px[j] - cx;
            const float dy = py[j] - cy;
            const float dz = pz[j] - cz;
            // match reference rounding: no fma contraction
            const float d = __fadd_rn(__fadd_rn(__fmul_rn(dx, dx), __fmul_rn(dy, dy)),
                                      __fmul_rn(dz, dz));
            const float m = fminf(md[j], d);
            md[j] = m;
            if (m > best) { best = m; bi = j * FPS_T + tid; }  // strict >: lowest p per thread
        }
        // pack (value, ~idx); min_d >= 0 so float-bits compare == float compare
        unsigned long long key =
            ((unsigned long long)__float_as_uint(best) << 32) | (unsigned)(~bi);
        key = wave_max_key(key);

        const int par = s & 1;
        if (lane == 63) pw[par][wid] = key;
        __syncthreads();
        // every thread redundantly reduces the 4 wave partials (broadcast reads)
        unsigned long long bk = pw[par][0];
#pragma unroll
        for (int w = 1; w < FPS_W; w++) {
            const unsigned long long v = pw[par][w];
            if (v > bk) bk = v;
        }
        bix = (int)(~(unsigned)bk);

        if (tid == 0) {
            fps_idx[b * NSAMP + s] = bix;
            out_xyz[(size_t)b * 3 * NSAMP + 0 * NSAMP + s] = sx[bix];
            out_xyz[(size_t)b * 3 * NSAMP + 1 * NSAMP + s] = sy[bix];
            out_xyz[(size_t)b * 3 * NSAMP + 2 * NSAMP + s] = sz[bix];
        }
    }
}

// ---------------------------------------------------------------------------
// Kernel 2: ball query. One wave (64 lanes) per query point.
// ---------------------------------------------------------------------------
__global__ __launch_bounds__(256) void ballq_kernel(const float* __restrict__ xyz,
                                                    const int* __restrict__ fps_idx,
                                                    int* __restrict__ grp) {
    const int q    = blockIdx.x * 4 + (threadIdx.x >> 6);
    const int lane = threadIdx.x & 63;
    const int b    = q >> 10;       // / NSAMP
    const int c    = fps_idx[q];

    const float* base = xyz + (size_t)b * NPTS * 3;
    const float cx = base[c * 3 + 0];
    const float cy = base[c * 3 + 1];
    const float cz = base[c * 3 + 2];
    const float r2 = 0.04f;         // f32(0.2*0.2)

    int* g = grp + (size_t)q * KNB;
    int cnt = 0;
    int firstCand = 0x7fffffff;

    for (int bp = 0; bp < NPTS && cnt < KNB; bp += 64) {
        const int p = bp + lane;
        const float dx = base[p * 3 + 0] - cx;
        const float dy = base[p * 3 + 1] - cy;
        const float dz = base[p * 3 + 2] - cz;
        const float d = __fadd_rn(__fadd_rn(__fmul_rn(dx, dx), __fmul_rn(dy, dy)),
                                  __fmul_rn(dz, dz));
        const bool ok = !(d > r2);
        const unsigned long long m = __ballot(ok);
        const int rank = cnt + (int)__popcll(m & ((1ull << lane) - 1ull));
        if (ok && rank < KNB) g[rank] = p;
        if (ok && rank == 0) firstCand = p;
        cnt += (int)__popcll(m);
    }

    const int found = cnt < KNB ? cnt : KNB;
    if (found < KNB) {
#pragma unroll
        for (int off = 32; off > 0; off >>= 1) {
            const int o = __shfl_xor(firstCand, off);
            firstCand = o < firstCand ? o : firstCand;
        }
        for (int r = found + lane; r < KNB; r += 64) g[r] = firstCand;
    }
}

// ---------------------------------------------------------------------------
// Kernel 3: gather + MLP(64->64 relu, 64->128 relu) + max over 32 samples.
// One wave per query; lane = channel.
// ---------------------------------------------------------------------------
__global__ __launch_bounds__(256) void mlp_kernel(const float* __restrict__ features,
                                                  const int* __restrict__ grp,
                                                  const float* __restrict__ W1,
                                                  const float* __restrict__ b1,
                                                  const float* __restrict__ W2,
                                                  const float* __restrict__ b2,
                                                  float* __restrict__ out_pts) {
    const int wid  = threadIdx.x >> 6;
    const int lane = threadIdx.x & 63;
    const int q    = blockIdx.x * 4 + wid;
    const int b    = q >> 10;
    const int s    = q & 1023;

    __shared__ float xls[4][KNB][DFEAT];   // 32 KB
    __shared__ float h1s[4][DFEAT];        // 1 KB

    float w1r[64], w2ra[64], w2rb[64];
    {
        const float4* W1v = (const float4*)(W1 + (size_t)lane * 64);
        const float4* W2a = (const float4*)(W2 + (size_t)lane * 64);
        const float4* W2b = (const float4*)(W2 + (size_t)(lane + 64) * 64);
#pragma unroll
        for (int i = 0; i < 16; i++) {
            float4 v = W1v[i];
            w1r[4 * i] = v.x; w1r[4 * i + 1] = v.y; w1r[4 * i + 2] = v.z; w1r[4 * i + 3] = v.w;
            v = W2a[i];
            w2ra[4 * i] = v.x; w2ra[4 * i + 1] = v.y; w2ra[4 * i + 2] = v.z; w2ra[4 * i + 3] = v.w;
            v = W2b[i];
            w2rb[4 * i] = v.x; w2rb[4 * i + 1] = v.y; w2rb[4 * i + 2] = v.z; w2rb[4 * i + 3] = v.w;
        }
    }
    const float b1r  = b1[lane];
    const float b2ra = b2[lane];
    const float b2rb = b2[lane + 64];

    int gi = 0;
    if (lane < KNB) gi = grp[(size_t)q * KNB + lane];
    const float* fb = features + (size_t)b * NPTS * DFEAT;
    for (int k = 0; k < KNB; k++) {
        const int idxk = __shfl(gi, k);
        xls[wid][k][lane] = fb[(size_t)idxk * DFEAT + lane];
    }
    __syncthreads();

    float m0 = 0.0f, m1 = 0.0f;   // relu outputs >= 0
    for (int k = 0; k < KNB; k++) {
        float acc = b1r;
        const float4* xk = (const float4*)xls[wid][k];
#pragma unroll
        for (int i = 0; i < 16; i++) {
            const float4 v = xk[i];
            acc = fmaf(v.x, w1r[4 * i], acc);
            acc = fmaf(v.y, w1r[4 * i + 1], acc);
            acc = fmaf(v.z, w1r[4 * i + 2], acc);
            acc = fmaf(v.w, w1r[4 * i + 3], acc);
        }
        const float h = fmaxf(acc, 0.0f);
        __syncthreads();
        h1s[wid][lane] = h;
        __syncthreads();
        float a0 = b2ra, a1 = b2rb;
        const float4* hv4 = (const float4*)h1s[wid];
#pragma unroll
        for (int i = 0; i < 16; i++) {
            const float4 v = hv4[i];
            a0 = fmaf(v.x, w2ra[4 * i], a0);
            a0 = fmaf(v.y, w2ra[4 * i + 1], a0);
            a0 = fmaf(v.z, w2ra[4 * i + 2], a0);
            a0 = fmaf(v.w, w2ra[4 * i + 3], a0);
            a1 = fmaf(v.x, w2rb[4 * i], a1);
            a1 = fmaf(v.y, w2rb[4 * i + 1], a1);
            a1 = fmaf(v.z, w2rb[4 * i + 2], a1);
            a1 = fmaf(v.w, w2rb[4 * i + 3], a1);
        }
        m0 = fmaxf(m0, fmaxf(a0, 0.0f));
        m1 = fmaxf(m1, fmaxf(a1, 0.0f));
    }

    out_pts[(size_t)b * 128 * NSAMP + (size_t)lane * NSAMP + s]        = m0;
    out_pts[(size_t)b * 128 * NSAMP + (size_t)(lane + 64) * NSAMP + s] = m1;
}

extern "C" void kernel_launch(void* const* d_in, const int* in_sizes, int n_in,
                              void* d_out, int out_size, void* d_ws, size_t ws_size,
                              hipStream_t stream) {
    const float* xyz      = (const float*)d_in[0];
    const float* features = (const float*)d_in[1];
    const float* W1       = (const float*)d_in[2];
    const float* b1       = (const float*)d_in[3];
    const float* W2       = (const float*)d_in[4];
    const float* b2       = (const float*)d_in[5];

    float* out_xyz = (float*)d_out;                                  // [B,3,S]
    float* out_pts = (float*)d_out + (size_t)BATCH * 3 * NSAMP;      // [B,128,S]

    int* fps_idx = (int*)d_ws;                                       // [B,S]
    int* grp     = fps_idx + (size_t)BATCH * NSAMP;                  // [B,S,32]

    fps_kernel<<<BATCH, FPS_T, 0, stream>>>(xyz, fps_idx, out_xyz);
    ballq_kernel<<<BATCH * NSAMP / 4, 256, 0, stream>>>(xyz, fps_idx, grp);
    mlp_kernel<<<BATCH * NSAMP / 4, 256, 0, stream>>>(features, grp, W1, b1, W2, b2, out_pts);
}